// Round 1
// baseline (1719.984 us; speedup 1.0000x reference)
//
#include <hip/hip_runtime.h>
#include <math.h>

#define NUM_NODES 50000
#define NUM_EDGES 1600000
#define DIM 128
#define EDGE_DIM 16
#define KPAD 288          // 272 padded to 18*16
#define NKT1 18           // k-tiles (16) for GEMM1
#define NKT2 8            // k-tiles (16) for GEMM2
#define MT 128            // edges per tile
#define ROWSTRIDE 296     // shorts per x-row in LDS (592 B: 16B-aligned, bank-friendly)

typedef short bf16x8 __attribute__((ext_vector_type(8)));
typedef float floatx16 __attribute__((ext_vector_type(16)));
typedef unsigned short ushort4v __attribute__((ext_vector_type(4)));

__device__ __forceinline__ unsigned short f2b(float f) {
    unsigned u = __builtin_bit_cast(unsigned, f);
    u += 0x7FFFu + ((u >> 16) & 1u);   // round-to-nearest-even
    return (unsigned short)(u >> 16);
}

// ---- Repack W1/W2 (fp32 [K][N]) -> bf16 MFMA B-fragment order -----------
// Fragment order: [kt][nb][lane][8], lane: n = nb*32 + (lane&31),
// k = kt*16 + (lane>>5)*8 + j.  W1 zero-padded for k >= 272.
__global__ void prep_kernel(const float* __restrict__ W1, const float* __restrict__ W2,
                            short* __restrict__ W1f, short* __restrict__ W2f)
{
    int gid = blockIdx.x * 256 + threadIdx.x;
    if (gid < NKT1 * 4 * 64) {                       // 4608 fragment-lanes for W1
        int lane = gid & 63, nb = (gid >> 6) & 3, kt = gid >> 8;
        int n = nb * 32 + (lane & 31);
        int kbase = kt * 16 + (lane >> 5) * 8;
        #pragma unroll
        for (int j = 0; j < 8; ++j) {
            int k = kbase + j;
            W1f[gid * 8 + j] = (k < 272) ? (short)f2b(W1[(size_t)k * DIM + n]) : (short)0;
        }
    } else if (gid < NKT1 * 4 * 64 + NKT2 * 4 * 64) { // 2048 fragment-lanes for W2
        int g2 = gid - NKT1 * 4 * 64;
        int lane = g2 & 63, nb = (g2 >> 6) & 3, kt = g2 >> 8;
        int n = nb * 32 + (lane & 31);
        int kbase = kt * 16 + (lane >> 5) * 8;
        #pragma unroll
        for (int j = 0; j < 8; ++j)
            W2f[g2 * 8 + j] = (short)f2b(W2[(size_t)(kbase + j) * DIM + n]);
    }
}

// ---- Fused edge MLP: gather -> GEMM1 -> GELU -> GEMM2 -> scatter-add ----
__global__ __launch_bounds__(256, 2) void edge_kernel(
    const float* __restrict__ h, const int* __restrict__ src, const int* __restrict__ dst,
    const float* __restrict__ ea, const short* __restrict__ W1f, const short* __restrict__ W2f,
    const float* __restrict__ pb1, const float* __restrict__ pb2, float* __restrict__ agg)
{
    __shared__ __align__(16) short xbuf[MT * ROWSTRIDE];   // 75776 B
    __shared__ int srcl[MT];
    __shared__ int dstl[MT];
    short* hdnf = xbuf;                                    // overlay after GEMM1 (32768 B)

    const int tid = threadIdx.x;
    const long long base = (long long)blockIdx.x * MT;

    if (tid < MT) srcl[tid] = src[base + tid];
    else          dstl[tid - MT] = dst[base + (tid - MT)];
    __syncthreads();

    // gather + fp32->bf16: 128 rows x 74 chunks (4 floats each); chunks >= 68 are zero pad
    for (int it = 0; it < 37; ++it) {
        int i = tid + it * 256;
        int row = i / 74, c = i - row * 74;
        float4 v = make_float4(0.f, 0.f, 0.f, 0.f);
        if (c < 32)      v = *(const float4*)(h + (size_t)srcl[row] * DIM + c * 4);
        else if (c < 64) v = *(const float4*)(h + (size_t)dstl[row] * DIM + (c - 32) * 4);
        else if (c < 68) v = *(const float4*)(ea + (size_t)(base + row) * EDGE_DIM + (c - 64) * 4);
        ushort4v o;
        o.x = f2b(v.x); o.y = f2b(v.y); o.z = f2b(v.z); o.w = f2b(v.w);
        *(ushort4v*)&xbuf[row * ROWSTRIDE + c * 4] = o;
    }
    __syncthreads();

    const int lane = tid & 63, wave = tid >> 6;
    const int rm = wave >> 1, rn = wave & 1;      // 2x2 wave grid over 128x128
    const int lm = lane & 31, half = lane >> 5;

    // ---------------- GEMM1: x[128,288] @ W1[288,128] ----------------
    floatx16 acc[2][2] = {};
    #pragma unroll
    for (int kt = 0; kt < NKT1; ++kt) {
        bf16x8 a0 = *(const bf16x8*)&xbuf[(rm * 64 + lm) * ROWSTRIDE + kt * 16 + half * 8];
        bf16x8 a1 = *(const bf16x8*)&xbuf[(rm * 64 + 32 + lm) * ROWSTRIDE + kt * 16 + half * 8];
        bf16x8 b0 = *(const bf16x8*)(W1f + ((kt * 4 + rn * 2 + 0) * 64 + lane) * 8);
        bf16x8 b1 = *(const bf16x8*)(W1f + ((kt * 4 + rn * 2 + 1) * 64 + lane) * 8);
        acc[0][0] = __builtin_amdgcn_mfma_f32_32x32x16_bf16(a0, b0, acc[0][0], 0, 0, 0);
        acc[0][1] = __builtin_amdgcn_mfma_f32_32x32x16_bf16(a0, b1, acc[0][1], 0, 0, 0);
        acc[1][0] = __builtin_amdgcn_mfma_f32_32x32x16_bf16(a1, b0, acc[1][0], 0, 0, 0);
        acc[1][1] = __builtin_amdgcn_mfma_f32_32x32x16_bf16(a1, b1, acc[1][1], 0, 0, 0);
    }
    __syncthreads();   // all GEMM1 LDS reads done before hdnf overlay writes

    // ---------------- bias + exact GELU -> hdn (A-fragment order in LDS) ----
    // C/D layout (verified): col = lane&31, row = (reg&3) + 8*(reg>>2) + 4*(lane>>5)
    float bb1_0 = pb1[rn * 64 + lm];
    float bb1_1 = pb1[rn * 64 + 32 + lm];
    #pragma unroll
    for (int i = 0; i < 2; ++i) {
        #pragma unroll
        for (int j = 0; j < 2; ++j) {
            float bb = j ? bb1_1 : bb1_0;
            int kg = rn * 64 + j * 32 + lm;           // hdn column = GEMM2 k
            int ktl = kg >> 4;
            int lrbase = 32 * ((lm >> 3) & 1);
            int jr = lm & 7;
            #pragma unroll
            for (int r = 0; r < 16; ++r) {
                int rr = (r & 3) + 8 * (r >> 2) + 4 * half;
                float v = acc[i][j][r] + bb;
                float g = 0.5f * v * (1.f + erff(v * 0.70710678118f));
                hdnf[(((rm * 2 + i) * 8 + ktl) * 64 + rr + lrbase) * 8 + jr] = (short)f2b(g);
            }
        }
    }
    __syncthreads();

    // ---------------- GEMM2: hdn[128,128] @ W2[128,128] ----------------
    floatx16 acc2[2][2] = {};
    #pragma unroll
    for (int kt = 0; kt < NKT2; ++kt) {
        bf16x8 a0 = *(const bf16x8*)&hdnf[(((rm * 2 + 0) * 8 + kt) * 64 + lane) * 8];
        bf16x8 a1 = *(const bf16x8*)&hdnf[(((rm * 2 + 1) * 8 + kt) * 64 + lane) * 8];
        bf16x8 b0 = *(const bf16x8*)(W2f + ((kt * 4 + rn * 2 + 0) * 64 + lane) * 8);
        bf16x8 b1 = *(const bf16x8*)(W2f + ((kt * 4 + rn * 2 + 1) * 64 + lane) * 8);
        acc2[0][0] = __builtin_amdgcn_mfma_f32_32x32x16_bf16(a0, b0, acc2[0][0], 0, 0, 0);
        acc2[0][1] = __builtin_amdgcn_mfma_f32_32x32x16_bf16(a0, b1, acc2[0][1], 0, 0, 0);
        acc2[1][0] = __builtin_amdgcn_mfma_f32_32x32x16_bf16(a1, b0, acc2[1][0], 0, 0, 0);
        acc2[1][1] = __builtin_amdgcn_mfma_f32_32x32x16_bf16(a1, b1, acc2[1][1], 0, 0, 0);
    }

    // ---------------- bias + scatter-add to agg[dst] ----------------
    float bb2_0 = pb2[rn * 64 + lm];
    float bb2_1 = pb2[rn * 64 + 32 + lm];
    #pragma unroll
    for (int i = 0; i < 2; ++i) {
        #pragma unroll
        for (int j = 0; j < 2; ++j) {
            float bb = j ? bb2_1 : bb2_0;
            int n = rn * 64 + j * 32 + lm;
            #pragma unroll
            for (int r = 0; r < 16; ++r) {
                int rr = (r & 3) + 8 * (r >> 2) + 4 * half;
                int erow = rm * 64 + i * 32 + rr;
                int d = dstl[erow];
                atomicAdd(&agg[(size_t)d * DIM + n], acc2[i][j][r] + bb);
            }
        }
    }
}

// ---- LayerNorm over h + agg (in place on agg = d_out) -------------------
__global__ __launch_bounds__(256) void ln_kernel(
    const float* __restrict__ h, float* __restrict__ io,
    const float* __restrict__ gamma, const float* __restrict__ beta)
{
    int wave = threadIdx.x >> 6, lane = threadIdx.x & 63;
    int node = blockIdx.x * 4 + wave;
    const float2* h2 = (const float2*)(h + (size_t)node * DIM);
    float2* o2 = (float2*)(io + (size_t)node * DIM);
    float2 a = o2[lane];
    float2 b = h2[lane];
    float x0 = a.x + b.x, x1 = a.y + b.y;
    float s = x0 + x1;
    float ss = x0 * x0 + x1 * x1;
    #pragma unroll
    for (int m = 1; m < 64; m <<= 1) {
        s  += __shfl_xor(s, m, 64);
        ss += __shfl_xor(ss, m, 64);
    }
    float mu = s * (1.f / DIM);
    float var = ss * (1.f / DIM) - mu * mu;
    float rs = rsqrtf(var + 1e-5f);
    float g0 = gamma[lane * 2], g1 = gamma[lane * 2 + 1];
    float e0 = beta[lane * 2],  e1 = beta[lane * 2 + 1];
    float2 outv;
    outv.x = (x0 - mu) * rs * g0 + e0;
    outv.y = (x1 - mu) * rs * g1 + e1;
    o2[lane] = outv;
}

extern "C" void kernel_launch(void* const* d_in, const int* in_sizes, int n_in,
                              void* d_out, int out_size, void* d_ws, size_t ws_size,
                              hipStream_t stream)
{
    const float* h     = (const float*)d_in[0];
    const int*   src   = (const int*)d_in[1];
    const int*   dst   = (const int*)d_in[2];
    const float* ea    = (const float*)d_in[3];
    const float* W1    = (const float*)d_in[4];
    const float* pb1   = (const float*)d_in[5];
    const float* W2    = (const float*)d_in[6];
    const float* pb2   = (const float*)d_in[7];
    const float* gamma = (const float*)d_in[8];
    const float* beta  = (const float*)d_in[9];
    float* out = (float*)d_out;

    short* W1f = (short*)d_ws;                       // 18*4*64*8 shorts = 73728 B
    short* W2f = (short*)d_ws + NKT1 * 4 * 64 * 8;   // 8*4*64*8 shorts  = 32768 B

    // d_out doubles as the fp32 scatter accumulator; zero it every call
    hipMemsetAsync(d_out, 0, (size_t)NUM_NODES * DIM * sizeof(float), stream);

    prep_kernel<<<26, 256, 0, stream>>>(W1, W2, W1f, W2f);
    edge_kernel<<<NUM_EDGES / MT, 256, 0, stream>>>(h, src, dst, ea, W1f, W2f, pb1, pb2, out);
    ln_kernel<<<NUM_NODES / 4, 256, 0, stream>>>(h, out, gamma, beta);
}